// Round 4
// baseline (70.157 us; speedup 1.0000x reference)
//
#include <hip/hip_runtime.h>

// Problem constants (match reference)
#define B_SZ   2
#define T_CTX  1024
#define E_IN   256
#define D_QK   64
#define DV_OUT 64
#define NROWS  (B_SZ * T_CTX)
#define RPB    4   // rows per proj block

// ---------------------------------------------------------------------------
// Kernel 1: projections, 4 rows per block, one row per wave, software-
// pipelined e-loops (prefetch next W/x pair while FMA-ing current).
//   q = relu(x@Wq+bq); k = relu(x@Wk+bk); v = x@Wv+bv
//   qpb = q@W1[:64] + b1   (row-major [row][d])
//   kpt = (k@W1[64:])^T    (TRANSPOSED: [d][row])
// ---------------------------------------------------------------------------
__global__ __launch_bounds__(256) void proj_kernel(
    const float* __restrict__ x,
    const float* __restrict__ Wq, const float* __restrict__ bq,
    const float* __restrict__ Wk, const float* __restrict__ bk,
    const float* __restrict__ Wv, const float* __restrict__ bv,
    const float* __restrict__ W1, const float* __restrict__ b1,
    float* __restrict__ qpb, float* __restrict__ kpt, float* __restrict__ v)
{
    __shared__ float xs[RPB * E_IN];
    __shared__ float qs[RPB * D_QK];
    __shared__ float ks[RPB * D_QK];
    __shared__ float kps[RPB * D_QK];

    const int row0 = blockIdx.x * RPB;
    const int t    = threadIdx.x;

    #pragma unroll
    for (int idx = t; idx < RPB * E_IN; idx += 256)
        xs[idx] = x[(size_t)row0 * E_IN + idx];
    __syncthreads();

    const int d = t & 63;
    const int r = t >> 6;                  // wave -> row
    const float* xrow = &xs[r * E_IN];
    const float* pq = Wq + d;
    const float* pk = Wk + d;
    const float* pv = Wv + d;

    // ---- stage 1: q/k/v projections, 2-deep pipelined over e-pairs ----
    float aq0 = 0.f, aq1 = 0.f, ak0 = 0.f, ak1 = 0.f, av0 = 0.f, av1 = 0.f;
    float wq0 = pq[0], wq1 = pq[D_QK];
    float wk0 = pk[0], wk1 = pk[D_QK];
    float wv0 = pv[0], wv1 = pv[DV_OUT];
    float x0  = xrow[0], x1v = xrow[1];
    #pragma unroll 4
    for (int e = 0; e < E_IN - 2; e += 2) {
        float nq0 = pq[(e + 2) * D_QK],  nq1 = pq[(e + 3) * D_QK];
        float nk0 = pk[(e + 2) * D_QK],  nk1 = pk[(e + 3) * D_QK];
        float nv0 = pv[(e + 2) * DV_OUT], nv1 = pv[(e + 3) * DV_OUT];
        float nx0 = xrow[e + 2], nx1 = xrow[e + 3];
        aq0 += x0 * wq0; aq1 += x1v * wq1;
        ak0 += x0 * wk0; ak1 += x1v * wk1;
        av0 += x0 * wv0; av1 += x1v * wv1;
        wq0 = nq0; wq1 = nq1; wk0 = nk0; wk1 = nk1; wv0 = nv0; wv1 = nv1;
        x0 = nx0; x1v = nx1;
    }
    aq0 += x0 * wq0; aq1 += x1v * wq1;
    ak0 += x0 * wk0; ak1 += x1v * wk1;
    av0 += x0 * wv0; av1 += x1v * wv1;

    qs[r * D_QK + d] = fmaxf(aq0 + aq1 + bq[d], 0.f);
    ks[r * D_QK + d] = fmaxf(ak0 + ak1 + bk[d], 0.f);
    v[(size_t)(row0 + r) * DV_OUT + d] = av0 + av1 + bv[d];
    __syncthreads();

    // ---- stage 2: qp/kp projections, same pipeline ----
    const float* qrow = &qs[r * D_QK];
    const float* krow = &ks[r * D_QK];
    const float* pw1 = W1 + d;                 // W1[e][d]
    const float* pw2 = W1 + D_QK * D_QK + d;   // W1[64+e][d]
    float ap0 = 0.f, ap1 = 0.f, bp0 = 0.f, bp1 = 0.f;
    float u0 = pw1[0], u1 = pw1[D_QK];
    float s0 = pw2[0], s1 = pw2[D_QK];
    float qa = qrow[0], qb = qrow[1], ka = krow[0], kb = krow[1];
    #pragma unroll 4
    for (int e = 0; e < D_QK - 2; e += 2) {
        float nu0 = pw1[(e + 2) * D_QK], nu1 = pw1[(e + 3) * D_QK];
        float ns0 = pw2[(e + 2) * D_QK], ns1 = pw2[(e + 3) * D_QK];
        float nqa = qrow[e + 2], nqb = qrow[e + 3];
        float nka = krow[e + 2], nkb = krow[e + 3];
        ap0 += qa * u0; ap1 += qb * u1;
        bp0 += ka * s0; bp1 += kb * s1;
        u0 = nu0; u1 = nu1; s0 = ns0; s1 = ns1;
        qa = nqa; qb = nqb; ka = nka; kb = nkb;
    }
    ap0 += qa * u0; ap1 += qb * u1;
    bp0 += ka * s0; bp1 += kb * s1;

    qpb[(size_t)(row0 + r) * D_QK + d] = ap0 + ap1 + b1[d];
    kps[r * D_QK + d] = bp0 + bp1;
    __syncthreads();

    // transposed kp write: 16B per lane
    if (t < D_QK) {
        float4 kq = make_float4(kps[0 * D_QK + t], kps[1 * D_QK + t],
                                kps[2 * D_QK + t], kps[3 * D_QK + t]);
        *(float4*)&kpt[(size_t)t * NROWS + row0] = kq;
    }
}

// ---------------------------------------------------------------------------
// Kernel 2: paired-row scored attention, TRANSPOSED kp, software-pipelined.
// Block = (b, pair ii): query rows i1=ii, i2=T-1-ii. Thread t owns j-quad
// [4t, 4t+3]. Score loop: fully unrolled 16 d-groups with register double
// buffering (next group's 4 global float4 + 3 LDS b128 issued before current
// group's 96 VALU ops). PV: float2-over-dv, 2 rows per wave-iter, 2-deep
// register pipeline.
// ---------------------------------------------------------------------------
__global__ __launch_bounds__(256, 4) void attn_kernel(
    const float* __restrict__ qpb, const float* __restrict__ kpt,
    const float* __restrict__ v,
    const float* __restrict__ W2, const float* __restrict__ b2,
    float* __restrict__ out)
{
    __shared__ float q1s[D_QK], q2s[D_QK], w2s[D_QK];
    __shared__ float scp[2 * T_CTX];            // interleaved {w1_j, w2_j}
    __shared__ float red[16];
    __shared__ float part1[4][DV_OUT], part2[4][DV_OUT];

    const int blk = blockIdx.x;
    const int b   = blk >> 9;
    const int ii  = blk & 511;
    const int i1  = ii, i2 = T_CTX - 1 - ii;
    const int n1  = i1 + 1, n2 = i2 + 1;        // n1+n2 = T+1; n2 >= 513
    const int t    = threadIdx.x;
    const int lane = t & 63;
    const int wave = t >> 6;
    const size_t base = (size_t)b * T_CTX;

    if (t < D_QK) {
        q1s[t] = qpb[(base + i1) * D_QK + t];
        q2s[t] = qpb[(base + i2) * D_QK + t];
        w2s[t] = W2[t];
    }
    __syncthreads();

    const float bias2 = b2[0];
    const int j0 = 4 * t;

    float a10 = 0.f, a11 = 0.f, a12 = 0.f, a13 = 0.f;
    float a20 = 0.f, a21 = 0.f, a22 = 0.f, a23 = 0.f;
    const float* kpb = kpt + base + j0;

#define ACC2(kv, q1c, q2c, wc) do {            \
    a10 += fmaxf(q1c + kv.x, 0.f) * wc;        \
    a11 += fmaxf(q1c + kv.y, 0.f) * wc;        \
    a12 += fmaxf(q1c + kv.z, 0.f) * wc;        \
    a13 += fmaxf(q1c + kv.w, 0.f) * wc;        \
    a20 += fmaxf(q2c + kv.x, 0.f) * wc;        \
    a21 += fmaxf(q2c + kv.y, 0.f) * wc;        \
    a22 += fmaxf(q2c + kv.z, 0.f) * wc;        \
    a23 += fmaxf(q2c + kv.w, 0.f) * wc; } while (0)
#define ACCB(kv, q2c, wc) do {                 \
    a20 += fmaxf(q2c + kv.x, 0.f) * wc;        \
    a21 += fmaxf(q2c + kv.y, 0.f) * wc;        \
    a22 += fmaxf(q2c + kv.z, 0.f) * wc;        \
    a23 += fmaxf(q2c + kv.w, 0.f) * wc; } while (0)

    if (j0 < n1) {                              // scores for both queries
        float4 ck0 = *(const float4*)(kpb + 0 * NROWS);
        float4 ck1 = *(const float4*)(kpb + 1 * NROWS);
        float4 ck2 = *(const float4*)(kpb + 2 * NROWS);
        float4 ck3 = *(const float4*)(kpb + 3 * NROWS);
        float4 cq1 = *(const float4*)&q1s[0];
        float4 cq2 = *(const float4*)&q2s[0];
        float4 cw  = *(const float4*)&w2s[0];
        #pragma unroll
        for (int g = 0; g < 16; ++g) {
            float4 nk0, nk1, nk2, nk3, nq1, nq2, nw;
            if (g < 15) {
                const float* kg = kpb + (size_t)(4 * g + 4) * NROWS;
                nk0 = *(const float4*)(kg + 0 * NROWS);
                nk1 = *(const float4*)(kg + 1 * NROWS);
                nk2 = *(const float4*)(kg + 2 * NROWS);
                nk3 = *(const float4*)(kg + 3 * NROWS);
                nq1 = *(const float4*)&q1s[4 * g + 4];
                nq2 = *(const float4*)&q2s[4 * g + 4];
                nw  = *(const float4*)&w2s[4 * g + 4];
            }
            ACC2(ck0, cq1.x, cq2.x, cw.x);
            ACC2(ck1, cq1.y, cq2.y, cw.y);
            ACC2(ck2, cq1.z, cq2.z, cw.z);
            ACC2(ck3, cq1.w, cq2.w, cw.w);
            if (g < 15) {
                ck0 = nk0; ck1 = nk1; ck2 = nk2; ck3 = nk3;
                cq1 = nq1; cq2 = nq2; cw = nw;
            }
        }
    } else if (j0 < n2) {                       // scores for q2 only
        float4 ck0 = *(const float4*)(kpb + 0 * NROWS);
        float4 ck1 = *(const float4*)(kpb + 1 * NROWS);
        float4 ck2 = *(const float4*)(kpb + 2 * NROWS);
        float4 ck3 = *(const float4*)(kpb + 3 * NROWS);
        float4 cq2 = *(const float4*)&q2s[0];
        float4 cw  = *(const float4*)&w2s[0];
        #pragma unroll
        for (int g = 0; g < 16; ++g) {
            float4 nk0, nk1, nk2, nk3, nq2, nw;
            if (g < 15) {
                const float* kg = kpb + (size_t)(4 * g + 4) * NROWS;
                nk0 = *(const float4*)(kg + 0 * NROWS);
                nk1 = *(const float4*)(kg + 1 * NROWS);
                nk2 = *(const float4*)(kg + 2 * NROWS);
                nk3 = *(const float4*)(kg + 3 * NROWS);
                nq2 = *(const float4*)&q2s[4 * g + 4];
                nw  = *(const float4*)&w2s[4 * g + 4];
            }
            ACCB(ck0, cq2.x, cw.x);
            ACCB(ck1, cq2.y, cw.y);
            ACCB(ck2, cq2.z, cw.z);
            ACCB(ck3, cq2.w, cw.w);
            if (g < 15) {
                ck0 = nk0; ck1 = nk1; ck2 = nk2; ck3 = nk3;
                cq2 = nq2; cw = nw;
            }
        }
    }
#undef ACC2
#undef ACCB

    float s1[4], s2[4];
    s1[0] = (j0 + 0 < n1) ? bias2 + a10 : -INFINITY;
    s1[1] = (j0 + 1 < n1) ? bias2 + a11 : -INFINITY;
    s1[2] = (j0 + 2 < n1) ? bias2 + a12 : -INFINITY;
    s1[3] = (j0 + 3 < n1) ? bias2 + a13 : -INFINITY;
    s2[0] = (j0 + 0 < n2) ? bias2 + a20 : -INFINITY;
    s2[1] = (j0 + 1 < n2) ? bias2 + a21 : -INFINITY;
    s2[2] = (j0 + 2 < n2) ? bias2 + a22 : -INFINITY;
    s2[3] = (j0 + 3 < n2) ? bias2 + a23 : -INFINITY;

    // ---- block max ----
    float m1l = fmaxf(fmaxf(s1[0], s1[1]), fmaxf(s1[2], s1[3]));
    float m2l = fmaxf(fmaxf(s2[0], s2[1]), fmaxf(s2[2], s2[3]));
    #pragma unroll
    for (int o = 32; o > 0; o >>= 1) {
        m1l = fmaxf(m1l, __shfl_xor(m1l, o, 64));
        m2l = fmaxf(m2l, __shfl_xor(m2l, o, 64));
    }
    if (lane == 0) { red[wave] = m1l; red[4 + wave] = m2l; }
    __syncthreads();
    const float m1 = fmaxf(fmaxf(red[0], red[1]), fmaxf(red[2], red[3]));
    const float m2 = fmaxf(fmaxf(red[4], red[5]), fmaxf(red[6], red[7]));

    // ---- exp (registers), interleaved store, block sum ----
    float p1[4], p2[4];
    #pragma unroll
    for (int e = 0; e < 4; ++e) {
        p1[e] = __expf(s1[e] - m1);             // masked -> exp(-inf) = 0
        p2[e] = __expf(s2[e] - m2);
    }
    if (j0 < n2) {
        float4 lo = make_float4(p1[0], p2[0], p1[1], p2[1]);
        float4 hi = make_float4(p1[2], p2[2], p1[3], p2[3]);
        *(float4*)&scp[2 * j0]     = lo;
        *(float4*)&scp[2 * j0 + 4] = hi;
    }
    float l1 = (p1[0] + p1[1]) + (p1[2] + p1[3]);
    float l2 = (p2[0] + p2[1]) + (p2[2] + p2[3]);
    #pragma unroll
    for (int o = 32; o > 0; o >>= 1) {
        l1 += __shfl_xor(l1, o, 64);
        l2 += __shfl_xor(l2, o, 64);
    }
    if (lane == 0) { red[8 + wave] = l1; red[12 + wave] = l2; }
    __syncthreads();
    const float denom1 = (red[8]  + red[9])  + (red[10] + red[11]);
    const float denom2 = (red[12] + red[13]) + (red[14] + red[15]);

    // ---- PV: float2 over dv, 2 rows per wave-iter, 2-deep pipeline ----
    const float2* scp2 = (const float2*)scp;    // scp2[j] = {w1_j, w2_j}
    const int half = lane >> 5;                 // half-wave -> row within pair
    const int dp   = (lane & 31) * 2;           // dv pair
    float x1a = 0.f, x1b = 0.f, x2a = 0.f, x2b = 0.f;
    int j = wave * 2;
    if (j + 1 < n2) {
        float2 vc = *(const float2*)&v[(base + j + half) * DV_OUT + dp];
        float2 wc = scp2[j + half];
        while (j + 9 < n2) {
            float2 vn = *(const float2*)&v[(base + j + 8 + half) * DV_OUT + dp];
            float2 wn = scp2[j + 8 + half];
            x1a += wc.x * vc.x; x1b += wc.x * vc.y;
            x2a += wc.y * vc.x; x2b += wc.y * vc.y;
            vc = vn; wc = wn; j += 8;
        }
        x1a += wc.x * vc.x; x1b += wc.x * vc.y;
        x2a += wc.y * vc.x; x2b += wc.y * vc.y;
        j += 8;
    }
    if (j < n2 && half == 0) {                  // leftover single row
        float2 vc = *(const float2*)&v[(base + j) * DV_OUT + dp];
        float2 wc = scp2[j];
        x1a += wc.x * vc.x; x1b += wc.x * vc.y;
        x2a += wc.y * vc.x; x2b += wc.y * vc.y;
    }
    // fold the two half-waves
    x1a += __shfl_xor(x1a, 32, 64); x1b += __shfl_xor(x1b, 32, 64);
    x2a += __shfl_xor(x2a, 32, 64); x2b += __shfl_xor(x2b, 32, 64);
    if (half == 0) {
        *(float2*)&part1[wave][dp] = make_float2(x1a, x1b);
        *(float2*)&part2[wave][dp] = make_float2(x2a, x2b);
    }
    __syncthreads();
    if (t < DV_OUT) {
        out[(base + i1) * DV_OUT + t] =
            ((part1[0][t] + part1[1][t]) + (part1[2][t] + part1[3][t])) / denom1;
    } else if (t < 2 * DV_OUT) {
        const int l = t - DV_OUT;
        out[(base + i2) * DV_OUT + l] =
            ((part2[0][l] + part2[1][l]) + (part2[2][l] + part2[3][l])) / denom2;
    }
}

extern "C" void kernel_launch(void* const* d_in, const int* in_sizes, int n_in,
                              void* d_out, int out_size, void* d_ws, size_t ws_size,
                              hipStream_t stream) {
    const float* x  = (const float*)d_in[0];
    const float* Wq = (const float*)d_in[1];
    const float* bq = (const float*)d_in[2];
    const float* Wk = (const float*)d_in[3];
    const float* bk = (const float*)d_in[4];
    const float* Wv = (const float*)d_in[5];
    const float* bv = (const float*)d_in[6];
    const float* W1 = (const float*)d_in[7];
    const float* b1 = (const float*)d_in[8];
    const float* W2 = (const float*)d_in[9];
    const float* b2 = (const float*)d_in[10];
    float* out = (float*)d_out;

    float* ws  = (float*)d_ws;
    float* qpb = ws;                              // NROWS * D_QK   (row-major)
    float* kpt = ws + (size_t)NROWS * D_QK;       // D_QK * NROWS   (TRANSPOSED)
    float* vv  = ws + (size_t)2 * NROWS * D_QK;   // NROWS * DV_OUT (row-major)

    proj_kernel<<<NROWS / RPB, 256, 0, stream>>>(x, Wq, bq, Wk, bk, Wv, bv,
                                                 W1, b1, qpb, kpt, vv);
    attn_kernel<<<B_SZ * (T_CTX / 2), 256, 0, stream>>>(qpb, kpt, vv, W2, b2, out);
}